// Round 8
// baseline (468.745 us; speedup 1.0000x reference)
//
#include <hip/hip_runtime.h>
#include <cstdint>
#include <cstddef>

// ---------------------------------------------------------------------------
// StokenAttention forward, MI355X. B=8, C=256, H=W=128, stoken 8x8 -> 16x16
// grid, n=256 stokens/batch, 64 px/stoken, NH=8 heads, HD=KD=32.
// R14 (single change vs R13): aff_agg memory-level parallelism.
//  - Phase 1 / phase 2: all 16 global float4 loads hoisted into register
//    arrays BEFORE the FMA chains (compile-time indexed -> stays in VGPRs).
//  - __launch_bounds__(256,4) -> (256,3): VGPR cap 168 so 16 loads can be
//    in flight (R13's bound forced VGPR=60 -> loads serialized ~4 deep;
//    with post-fill L3-cold x each phase ate 4 HBM latencies).
//  Rest identical to R13 (fused attn+PE, gemm32, split fold_div, scatter).
// ---------------------------------------------------------------------------

#define AFF_SCALE 0.0625f               // 256^-0.5
#define ATTN_SCALE 0.17677669529663687f // 32^-0.5

// DPP quad-perm add: v += lane(v ^ 1) / lane(v ^ 2) (VALU pipe).
__device__ __forceinline__ float dpp_add_xor1(float v) {
    int p = __builtin_amdgcn_update_dpp(0, __float_as_int(v), 0xB1, 0xF, 0xF, true);
    return v + __int_as_float(p);
}
__device__ __forceinline__ float dpp_add_xor2(float v) {
    int p = __builtin_amdgcn_update_dpp(0, __float_as_int(v), 0x4E, 0xF, 0xF, true);
    return v + __int_as_float(p);
}

// ---------------------------------------------------------------------------
// K1: stoken avg-pool. grid = B*C*16, block = 128. Channel-last
// [b][18][18][256]; interior (1..16)^2 only; ring handled by predication.
// ---------------------------------------------------------------------------
__global__ __launch_bounds__(128) void stoken_kernel(
    const float* __restrict__ x, float* __restrict__ stok_pad)
{
    int blk = blockIdx.x;
    int i  = blk & 15;
    int bc = blk >> 4;                 // b*256 + c
    int t  = threadIdx.x;              // col 0..127
    const float* xr = x + ((size_t)bc * 128 + i * 8) * 128 + t;
    float s = 0.f;
#pragma unroll
    for (int r = 0; r < 8; ++r) s += xr[r * 128];
    s += __shfl_down(s, 4, 64);
    s += __shfl_down(s, 2, 64);
    s += __shfl_down(s, 1, 64);
    if ((t & 7) == 0) {
        int j = t >> 3;  // 0..15
        int b = bc >> 8, c = bc & 255;
        stok_pad[(((size_t)b * 18 + (i + 1)) * 18 + (j + 1)) * 256 + c] =
            s * (1.f / 64.f);
    }
}

// ---------------------------------------------------------------------------
// K2: fused affinity + softmax + aggregation. grid = B*256, block = 256.
// LDS 14 KB. Pixels from global; 16 loads/phase held in flight.
// ---------------------------------------------------------------------------
__global__ __launch_bounds__(256, 3) void aff_agg_kernel(
    const float* __restrict__ x, const float* __restrict__ stok_pad,
    float* __restrict__ aff_g, float* __restrict__ asum_g,
    float* __restrict__ agg)
{
    __shared__ __align__(16) float sfs[9 * 260];   // sf9 [k][c]
    __shared__ __align__(16) float part[576];      // logits [p][k]
    __shared__ __align__(16) float affs[576];      // aff [k][p]

    int bid  = blockIdx.x;
    int xcd  = bid & 7, slot_ = bid >> 3;
    int pair = xcd * 128 + (slot_ >> 1);
    int m = pair & 7, i = (pair >> 3) & 15, b = pair >> 7;
    int j = m * 2 + (slot_ & 1);
    int bn = b * 256 + i * 16 + j;
    int t = threadIdx.x;

    // stage sf9 (channel-last, border-predicated): sfs[k][c]
    {
        const float* spT = stok_pad + (size_t)b * 324 * 256;
#pragma unroll
        for (int dy = 0; dy < 3; ++dy)
#pragma unroll
            for (int dx = 0; dx < 3; ++dx) {
                int r = i + dy, cn = j + dx;
                float v = 0.f;
                if ((unsigned)(r - 1) < 16u && (unsigned)(cn - 1) < 16u)
                    v = spT[((size_t)r * 18 + cn) * 256 + t];
                sfs[(dy * 3 + dx) * 260 + t] = v;
            }
    }
    part[t] = 0.f;
    part[t + 256] = 0.f;
    if (t < 64) part[t + 512] = 0.f;
    __syncthreads();

    int w = t >> 6, l = t & 63;

    // ---- phase 1: lane = (p-quad pq, c-16th cgl); acc[4p][9k].
    //      All 16 loads issued first (stay in flight), then FMA chain. ----
    {
        int pq = l >> 2, cgl = l & 3;
        int cbase = w * 64 + cgl * 16;
        int pi = pq >> 1, pj4 = (pq & 1) * 4;
        const float* xb = x + (size_t)(b * 256) * 16384
                            + (size_t)(i * 8 + pi) * 128 + j * 8 + pj4;

        float4 P[4][4];                // [c4i][c-sub] — compile-time indexed
#pragma unroll
        for (int c4i = 0; c4i < 4; ++c4i) {
            int c = cbase + c4i * 4;
#pragma unroll
            for (int cs = 0; cs < 4; ++cs)
                P[c4i][cs] = *(const float4*)&xb[(size_t)(c + cs) * 16384];
        }

        float acc[4][9];
#pragma unroll
        for (int ii = 0; ii < 4; ++ii)
#pragma unroll
            for (int k = 0; k < 9; ++k) acc[ii][k] = 0.f;

#pragma unroll
        for (int c4i = 0; c4i < 4; ++c4i) {
            int c = cbase + c4i * 4;
            const float4 p0 = P[c4i][0], p1 = P[c4i][1];
            const float4 p2 = P[c4i][2], p3 = P[c4i][3];
#pragma unroll
            for (int k = 0; k < 9; ++k) {
                const float4 sv = *(const float4*)&sfs[k * 260 + c];
                acc[0][k] += p0.x * sv.x + p1.x * sv.y + p2.x * sv.z + p3.x * sv.w;
                acc[1][k] += p0.y * sv.x + p1.y * sv.y + p2.y * sv.z + p3.y * sv.w;
                acc[2][k] += p0.z * sv.x + p1.z * sv.y + p2.z * sv.z + p3.z * sv.w;
                acc[3][k] += p0.w * sv.x + p1.w * sv.y + p2.w * sv.z + p3.w * sv.w;
            }
        }
#pragma unroll
        for (int ii = 0; ii < 4; ++ii)
#pragma unroll
            for (int k = 0; k < 9; ++k) {
                acc[ii][k] = dpp_add_xor1(acc[ii][k]);
                acc[ii][k] = dpp_add_xor2(acc[ii][k]);
            }
#pragma unroll
        for (int k = 0; k < 9; ++k) {
            float v01 = (cgl & 1) ? acc[1][k] : acc[0][k];
            float v23 = (cgl & 1) ? acc[3][k] : acc[2][k];
            float vk  = (cgl & 2) ? v23 : v01;
            atomicAdd(&part[l * 9 + k], vk);
        }
    }
    __syncthreads();

    // ---- phase 1.5: softmax over 9 (wave 0) ----
    if (t < 64) {
        float a[9];
        float mx = -1e30f;
#pragma unroll
        for (int k = 0; k < 9; ++k) {
            float v = part[t * 9 + k] * AFF_SCALE;
            a[k] = v;
            mx = fmaxf(mx, v);
        }
        float ssum = 0.f;
#pragma unroll
        for (int k = 0; k < 9; ++k) { a[k] = __expf(a[k] - mx); ssum += a[k]; }
        float inv = 1.f / ssum;
#pragma unroll
        for (int k = 0; k < 9; ++k) {
            a[k] *= inv;
            affs[k * 64 + t] = a[k];
            aff_g[(size_t)bn * 576 + k * 64 + t] = a[k];
        }
#pragma unroll
        for (int k = 0; k < 9; ++k) {
            float r = a[k];
            r += __shfl_down(r, 32, 64); r += __shfl_down(r, 16, 64);
            r += __shfl_down(r, 8, 64);  r += __shfl_down(r, 4, 64);
            r += __shfl_down(r, 2, 64);  r += __shfl_down(r, 1, 64);
            if (t == 0) asum_g[(size_t)bn * 9 + k] = r;
        }
    }
    __syncthreads();

    // ---- phase 2: lane = (c-quad cql, p-16th pq2); acc2[4c][9k].
    //      All 16 loads issued first, then FMA chain. ----
    {
        int cql = l >> 2, pq2 = l & 3;
        int cb2 = w * 64 + cql * 4;
        const float* xb = x + (size_t)(b * 256) * 16384 + (size_t)(i * 8) * 128 + j * 8;

        float4 Q[4][4];                // [pp][c-sub]
#pragma unroll
        for (int pp = 0; pp < 4; ++pp) {
            int p4 = pq2 * 4 + pp;
            int pi = p4 >> 1, pj4 = (p4 & 1) * 4;
            const float* xr = xb + (size_t)pi * 128 + pj4;
#pragma unroll
            for (int cs = 0; cs < 4; ++cs)
                Q[pp][cs] = *(const float4*)&xr[(size_t)(cb2 + cs) * 16384];
        }

        float acc2[4][9];
#pragma unroll
        for (int ii = 0; ii < 4; ++ii)
#pragma unroll
            for (int k = 0; k < 9; ++k) acc2[ii][k] = 0.f;

#pragma unroll
        for (int pp = 0; pp < 4; ++pp) {
            int p4 = pq2 * 4 + pp;
            const float4 q0 = Q[pp][0], q1 = Q[pp][1];
            const float4 q2 = Q[pp][2], q3 = Q[pp][3];
#pragma unroll
            for (int k = 0; k < 9; ++k) {
                const float4 av = *(const float4*)&affs[k * 64 + p4 * 4];
                acc2[0][k] += q0.x * av.x + q0.y * av.y + q0.z * av.z + q0.w * av.w;
                acc2[1][k] += q1.x * av.x + q1.y * av.y + q1.z * av.z + q1.w * av.w;
                acc2[2][k] += q2.x * av.x + q2.y * av.y + q2.z * av.z + q2.w * av.w;
                acc2[3][k] += q3.x * av.x + q3.y * av.y + q3.z * av.z + q3.w * av.w;
            }
        }
#pragma unroll
        for (int ii = 0; ii < 4; ++ii)
#pragma unroll
            for (int k = 0; k < 9; ++k) {
                acc2[ii][k] = dpp_add_xor1(acc2[ii][k]);
                acc2[ii][k] = dpp_add_xor2(acc2[ii][k]);
            }
        int cout = w * 64 + l;
#pragma unroll
        for (int k = 0; k < 9; ++k) {
            float v01 = (pq2 & 1) ? acc2[1][k] : acc2[0][k];
            float v23 = (pq2 & 1) ? acc2[3][k] : acc2[2][k];
            float vk  = (pq2 & 2) ? v23 : v01;
            agg[((size_t)bn * 9 + k) * 256 + cout] = vk;
        }
    }
}

// ---------------------------------------------------------------------------
// K3: fold(agg)/(fold(asum)+1e-12) -> sf[b][c][n]. grid = B*16*2 (b,y,chalf),
// block 256. c-split doubles block count; writes stay full 64B lines.
// ---------------------------------------------------------------------------
__global__ __launch_bounds__(256) void fold_div_kernel(
    const float* __restrict__ agg, const float* __restrict__ asum_g,
    float* __restrict__ sf)
{
    __shared__ float v[128 * 17];
    int bid = blockIdx.x;
    int b = bid >> 5, y = (bid >> 1) & 15, ch = bid & 1;
    int t = threadIdx.x;
    int cl = t & 127, xp = t >> 7;     // c-local, x-parity
    for (int it = 0; it < 8; ++it) {
        int x = it * 2 + xp;
        float af = 0.f, val = 0.f;
#pragma unroll
        for (int dy = 0; dy < 3; ++dy)
#pragma unroll
            for (int dx = 0; dx < 3; ++dx) {
                int ii = y + 1 - dy, jj = x + 1 - dx;
                if ((unsigned)ii < 16u && (unsigned)jj < 16u) {
                    int idx = (b * 256 + ii * 16 + jj) * 9 + dy * 3 + dx;
                    af  += asum_g[idx];                              // uniform
                    val += agg[(size_t)idx * 256 + ch * 128 + cl];   // coalesced
                }
            }
        v[cl * 17 + x] = val / (af + 1e-12f);
    }
    __syncthreads();
    int xw = t & 15, cw = t >> 4;      // 16 c-groups
#pragma unroll
    for (int itc = 0; itc < 8; ++itc) {
        int c_local = cw + itc * 16;
        sf[((size_t)b * 256 + ch * 128 + c_local) * 256 + y * 16 + xw] =
            v[c_local * 17 + xw];
    }
}

// ---------------------------------------------------------------------------
// K4/K7: GEMM 32o x 64n tiles. mode 0: out[b][o][n] -> [b][M][256].
// mode 1: write padded [b][18][18][256] at +1 spatial offset.
// qkv: grid (8,24,4)=768 blocks. proj: grid (8,8,4)=256 blocks.
// ---------------------------------------------------------------------------
__global__ __launch_bounds__(256) void gemm32(
    const float* __restrict__ A, const float* __restrict__ Bm,
    float* __restrict__ Cout, int M, int mode)
{
    __shared__ float As[32 * 36];   // [k][o], 32x32 tile, +4 pad
    __shared__ float Bs[32 * 64];
    int b = blockIdx.x, o0 = blockIdx.y * 32, n0 = blockIdx.z * 64;
    int t = threadIdx.x;
    int tr = t >> 4, tc = t & 15;      // tr: 16 o-pairs, tc: 16 n-quads
    const float* Bb = Bm + (size_t)b * 256 * 256;
    float acc[2][4];
#pragma unroll
    for (int ii = 0; ii < 2; ++ii)
#pragma unroll
        for (int jj = 0; jj < 4; ++jj) acc[ii][jj] = 0.f;

    for (int k0 = 0; k0 < 256; k0 += 32) {
        {
            int ol = t & 31, kq = (t >> 5) * 4;
            const float* Ap = A + (size_t)(o0 + ol) * 256 + k0 + kq;
            const float4 f = *(const float4*)&Ap[0];
            As[(kq + 0) * 36 + ol] = f.x; As[(kq + 1) * 36 + ol] = f.y;
            As[(kq + 2) * 36 + ol] = f.z; As[(kq + 3) * 36 + ol] = f.w;
        }
#pragma unroll
        for (int i2 = 0; i2 < 8; ++i2) {
            int e = t + i2 * 256;
            int kl = e >> 6, nl = e & 63;
            Bs[kl * 64 + nl] = Bb[(size_t)(k0 + kl) * 256 + n0 + nl];
        }
        __syncthreads();
#pragma unroll
        for (int kk = 0; kk < 32; ++kk) {
            const float2 av = *(const float2*)&As[kk * 36 + tr * 2];
            const float4 bv = *(const float4*)&Bs[kk * 64 + tc * 4];
            acc[0][0] += av.x * bv.x; acc[0][1] += av.x * bv.y;
            acc[0][2] += av.x * bv.z; acc[0][3] += av.x * bv.w;
            acc[1][0] += av.y * bv.x; acc[1][1] += av.y * bv.y;
            acc[1][2] += av.y * bv.z; acc[1][3] += av.y * bv.w;
        }
        __syncthreads();
    }

    if (mode == 0) {
#pragma unroll
        for (int ii = 0; ii < 2; ++ii) {
            int o = o0 + tr * 2 + ii;
            float4 st = make_float4(acc[ii][0], acc[ii][1], acc[ii][2], acc[ii][3]);
            *(float4*)&Cout[((size_t)b * M + o) * 256 + n0 + tc * 4] = st;
        }
    } else {
#pragma unroll
        for (int jj = 0; jj < 4; ++jj) {
            int n = n0 + tc * 4 + jj;
            int y = n >> 4, x = n & 15;
            float2 st = make_float2(acc[0][jj], acc[1][jj]);
            *(float2*)&Cout[(((size_t)b * 18 + 1 + y) * 18 + 1 + x) * 256 + o0 + tr * 2] = st;
        }
    }
}

// ---------------------------------------------------------------------------
// K5: attention + fused PE. grid = (8 b, 8 h, 8 n-tiles of 32), block = 256.
// V stays live in kv[] for the PE epilogue. LDS 69.8 KB -> 2 blocks/CU.
// ---------------------------------------------------------------------------
__global__ __launch_bounds__(256) void attn_kernel(
    const float* __restrict__ qkv, const float* __restrict__ w_pe,
    float* __restrict__ o_attn)
{
    __shared__ float kv[8192];        // K then V, [m*32+dd]
    __shared__ float op[256 * 33];    // per-(mq,n) partial O
    __shared__ float mxsm[512];       // per-(mq,n) {max, sum}
    __shared__ float wpe_s[288];      // w_pe[h][d][9]
    int b = blockIdx.x, h = blockIdx.y, nt = blockIdx.z;
    int t = threadIdx.x, nl = t & 31, mq = t >> 5;   // 8 m-groups of 32 keys
    int n = nt * 32 + nl;

    {
        int dd = t >> 3, mb = (t & 7) * 32;
        const float* krow = qkv + ((size_t)b * 768 + h * 96 + 32 + dd) * 256;
#pragma unroll
        for (int e4 = 0; e4 < 8; ++e4) {
            int m = mb + e4 * 4;
            const float4 kw = *(const float4*)&krow[m];
            kv[(m + 0) * 32 + dd] = kw.x; kv[(m + 1) * 32 + dd] = kw.y;
            kv[(m + 2) * 32 + dd] = kw.z; kv[(m + 3) * 32 + dd] = kw.w;
        }
    }
    for (int e = t; e < 288; e += 256) wpe_s[e] = w_pe[h * 288 + e];

    float q[32];
    {
        const float* qbase = qkv + ((size_t)b * 768 + h * 96) * 256 + n;
#pragma unroll
        for (int d = 0; d < 32; ++d) q[d] = qbase[(size_t)d * 256];
    }
    __syncthreads();

    float l[32];
#pragma unroll
    for (int e = 0; e < 32; ++e) {
        const float* kp = &kv[(mq * 32 + e) * 32];
        float s = 0.f;
#pragma unroll
        for (int d4 = 0; d4 < 8; ++d4) {
            const float4 kv4 = *(const float4*)&kp[d4 * 4];
            s += q[d4 * 4 + 0] * kv4.x + q[d4 * 4 + 1] * kv4.y +
                 q[d4 * 4 + 2] * kv4.z + q[d4 * 4 + 3] * kv4.w;
        }
        l[e] = s * ATTN_SCALE;
    }
    float mx = -1e30f;
#pragma unroll
    for (int e = 0; e < 32; ++e) mx = fmaxf(mx, l[e]);
    float sm = 0.f;
#pragma unroll
    for (int e = 0; e < 32; ++e) { l[e] = __expf(l[e] - mx); sm += l[e]; }
    __syncthreads();

    {
        int dd = t >> 3, mb = (t & 7) * 32;
        const float* vrow = qkv + ((size_t)b * 768 + h * 96 + 64 + dd) * 256;
#pragma unroll
        for (int e4 = 0; e4 < 8; ++e4) {
            int m = mb + e4 * 4;
            const float4 vw = *(const float4*)&vrow[m];
            kv[(m + 0) * 32 + dd] = vw.x; kv[(m + 1) * 32 + dd] = vw.y;
            kv[(m + 2) * 32 + dd] = vw.z; kv[(m + 3) * 32 + dd] = vw.w;
        }
    }
    __syncthreads();

    float oa[32];
#pragma unroll
    for (int d = 0; d < 32; ++d) oa[d] = 0.f;
#pragma unroll
    for (int e = 0; e < 32; ++e) {
        float pm = l[e];
        const float* vp = &kv[(mq * 32 + e) * 32];
#pragma unroll
        for (int d4 = 0; d4 < 8; ++d4) {
            const float4 vv = *(const float4*)&vp[d4 * 4];
            oa[d4 * 4 + 0] += pm * vv.x; oa[d4 * 4 + 1] += pm * vv.y;
            oa[d4 * 4 + 2] += pm * vv.z; oa[d4 * 4 + 3] += pm * vv.w;
        }
    }

    {
        int idx = mq * 32 + nl;
#pragma unroll
        for (int d = 0; d < 32; ++d) op[idx * 33 + d] = oa[d];
        mxsm[idx * 2 + 0] = mx;
        mxsm[idx * 2 + 1] = sm;
    }
    __syncthreads();

    if (t < 32) {
        float M2 = -1e30f;
#pragma unroll
        for (int q8 = 0; q8 < 8; ++q8) M2 = fmaxf(M2, mxsm[(q8 * 32 + t) * 2]);
        float w[8], S = 0.f;
#pragma unroll
        for (int q8 = 0; q8 < 8; ++q8) {
            w[q8] = __expf(mxsm[(q8 * 32 + t) * 2] - M2);
            S += mxsm[(q8 * 32 + t) * 2 + 1] * w[q8];
        }
        float inv = 1.f / S;
        int n2 = nt * 32 + t;
        int y0 = n2 >> 4, x0 = n2 & 15;
#pragma unroll
        for (int d = 0; d < 32; ++d) {
            float o = 0.f;
#pragma unroll
            for (int q8 = 0; q8 < 8; ++q8) o += op[(q8 * 32 + t) * 33 + d] * w[q8];
            float pe = 0.f;
#pragma unroll
            for (int ky = 0; ky < 3; ++ky)
#pragma unroll
                for (int kx = 0; kx < 3; ++kx) {
                    int yv = y0 + ky - 1, xv = x0 + kx - 1;
                    if ((unsigned)yv < 16u && (unsigned)xv < 16u)
                        pe += wpe_s[d * 9 + ky * 3 + kx] * kv[(yv * 16 + xv) * 32 + d];
                }
            o_attn[((size_t)b * 256 + h * 32 + d) * 256 + n2] = o * inv + pe;
        }
    }
}

// ---------------------------------------------------------------------------
// K8: scatter v3. grid = (b,i,pi) = 1024 blocks, block = 256.
// sfa staging border-predicated (pad ring never written -> select 0).
// ---------------------------------------------------------------------------
__global__ __launch_bounds__(256) void scatter_kernel(
    const float* __restrict__ sfa_pad, const float* __restrict__ aff_g,
    float* __restrict__ out)
{
    __shared__ float ss[3 * 18 * 40];   // [dy][col][idx=q*8+d], stride 40
    __shared__ float aff_s[16 * 577];   // [j][p*9+k], stride 577 (>=576)

    int blk = blockIdx.x;
    int pi = blk & 7, i = (blk >> 3) & 15, b = blk >> 7;
    int t = threadIdx.x;

    for (int e = t; e < 1728; e += 256) {
        int dy = e / 576, rem = e % 576;
        int col = rem >> 5, idx = rem & 31;
        int q = idx >> 3, d = idx & 7;
        int row = i + dy;
        float v = 0.f;
        if ((unsigned)(row - 1) < 16u && (unsigned)(col - 1) < 16u)
            v = sfa_pad[(((size_t)b * 18 + row) * 18 + col) * 256 + q * 64 + pi * 8 + d];
        ss[(dy * 18 + col) * 40 + idx] = v;
    }
    {
        const float* ag = aff_g + ((size_t)b * 256 + i * 16) * 576;
        for (int e = t; e < 9216; e += 256) {
            int j = e / 576, rem = e % 576;
            int k = rem >> 6, p = rem & 63;
            aff_s[j * 577 + p * 9 + k] = ag[j * 576 + rem];
        }
    }
    __syncthreads();

    int lane = t & 63, w = t >> 6;
    int j0 = lane >> 3, pj = lane & 7;
    int j1 = j0 + 8;

    float S0[4][9], S1[4][9];
#pragma unroll
    for (int q = 0; q < 4; ++q)
#pragma unroll
        for (int k = 0; k < 9; ++k) {
            int dy = k / 3, dx = k % 3;
            S0[q][k] = ss[(dy * 18 + j0 + dx) * 40 + q * 8 + pj];
            S1[q][k] = ss[(dy * 18 + j1 + dx) * 40 + q * 8 + pj];
        }

    int y = i * 8 + pi;
    size_t ob = (size_t)b * 256 * 16384 + (size_t)y * 128;
    const float* A0 = &aff_s[j0 * 577];
    const float* A1 = &aff_s[j1 * 577];
    for (int p = w * 16; p < w * 16 + 16; ++p) {
        float a0[9], a1[9];
#pragma unroll
        for (int k = 0; k < 9; ++k) { a0[k] = A0[p * 9 + k]; a1[k] = A1[p * 9 + k]; }
#pragma unroll
        for (int q = 0; q < 4; ++q) {
            int c2 = p * 4 + q;
            float v0 = 0.f, v1 = 0.f;
#pragma unroll
            for (int k = 0; k < 9; ++k) {
                v0 += S0[q][k] * a0[k];
                v1 += S1[q][k] * a1[k];
            }
            out[ob + (size_t)c2 * 16384 + lane] = v0;
            out[ob + (size_t)c2 * 16384 + 64 + lane] = v1;
        }
    }
}

// ---------------------------------------------------------------------------
// launch. Workspace (floats), 15.8 MB; agg (18.9 MB) lives in d_out scratch
// (dead before scatter writes out). No memsets (predicated pad rings).
// ---------------------------------------------------------------------------
extern "C" void kernel_launch(void* const* d_in, const int* in_sizes, int n_in,
                              void* d_out, int out_size, void* d_ws, size_t ws_size,
                              hipStream_t stream) {
    const float* x      = (const float*)d_in[0];
    const float* w_qkv  = (const float*)d_in[1];
    const float* w_pe   = (const float*)d_in[2];
    const float* w_proj = (const float*)d_in[3];
    float* out = (float*)d_out;
    float* agg = (float*)d_out;  // scratch: 18.9 MB << 134 MB, dead before scatter

    float* ws = (float*)d_ws;
    const size_t o_aff  = 0;
    const size_t o_asum = 1179648;
    const size_t o_pad  = 1198080;
    const size_t o_sf   = 1861632;
    const size_t o_qkv  = 2385920;

    stoken_kernel<<<8 * 256 * 16, 128, 0, stream>>>(x, ws + o_pad);
    aff_agg_kernel<<<8 * 256, 256, 0, stream>>>(x, ws + o_pad, ws + o_aff,
                                                ws + o_asum, agg);
    fold_div_kernel<<<8 * 32, 256, 0, stream>>>(agg, ws + o_asum, ws + o_sf);
    gemm32<<<dim3(8, 24, 4), 256, 0, stream>>>(w_qkv, ws + o_sf, ws + o_qkv, 768, 0);
    attn_kernel<<<dim3(8, 8, 8), 256, 0, stream>>>(ws + o_qkv, w_pe, ws + o_sf);
    gemm32<<<dim3(8, 8, 4), 256, 0, stream>>>(w_proj, ws + o_sf, ws + o_pad, 256, 1);
    scatter_kernel<<<8 * 16 * 8, 256, 0, stream>>>(ws + o_pad, ws + o_aff, out);
}

// Round 10
// 421.389 us; speedup vs baseline: 1.1124x; 1.1124x over previous
//
#include <hip/hip_runtime.h>
#include <cstdint>
#include <cstddef>

// ---------------------------------------------------------------------------
// StokenAttention forward, MI355X. B=8, C=256, H=W=128, stoken 8x8 -> 16x16
// grid, n=256 stokens/batch, 64 px/stoken, NH=8 heads, HD=KD=32.
// R16: R13 (last-known-good, 422.8 us) with EXACTLY ONE change:
//  - attn kv row stride 32 -> 36 floats. Fixes the measured 6.02M
//    bank-conflict cycles (PE epilogue read kv[m*32+d] was 32-way: 128B
//    stride -> all lanes one bank; stride 36 -> (4m+d)%32 -> 2-way = free).
//  R15's epilogue parallelization is REVERTED (post-timing divergence under
//  graph replay; root cause not identified -> minimal-delta discipline).
// ---------------------------------------------------------------------------

#define AFF_SCALE 0.0625f               // 256^-0.5
#define ATTN_SCALE 0.17677669529663687f // 32^-0.5

// DPP quad-perm add: v += lane(v ^ 1) / lane(v ^ 2) (VALU pipe).
__device__ __forceinline__ float dpp_add_xor1(float v) {
    int p = __builtin_amdgcn_update_dpp(0, __float_as_int(v), 0xB1, 0xF, 0xF, true);
    return v + __int_as_float(p);
}
__device__ __forceinline__ float dpp_add_xor2(float v) {
    int p = __builtin_amdgcn_update_dpp(0, __float_as_int(v), 0x4E, 0xF, 0xF, true);
    return v + __int_as_float(p);
}

// ---------------------------------------------------------------------------
// K1: stoken avg-pool. grid = B*C*16, block = 128. Channel-last
// [b][18][18][256]; interior (1..16)^2 only; ring handled by predication.
// ---------------------------------------------------------------------------
__global__ __launch_bounds__(128) void stoken_kernel(
    const float* __restrict__ x, float* __restrict__ stok_pad)
{
    int blk = blockIdx.x;
    int i  = blk & 15;
    int bc = blk >> 4;                 // b*256 + c
    int t  = threadIdx.x;              // col 0..127
    const float* xr = x + ((size_t)bc * 128 + i * 8) * 128 + t;
    float s = 0.f;
#pragma unroll
    for (int r = 0; r < 8; ++r) s += xr[r * 128];
    s += __shfl_down(s, 4, 64);
    s += __shfl_down(s, 2, 64);
    s += __shfl_down(s, 1, 64);
    if ((t & 7) == 0) {
        int j = t >> 3;  // 0..15
        int b = bc >> 8, c = bc & 255;
        stok_pad[(((size_t)b * 18 + (i + 1)) * 18 + (j + 1)) * 256 + c] =
            s * (1.f / 64.f);
    }
}

// ---------------------------------------------------------------------------
// K2: fused affinity + softmax + aggregation. grid = B*256, block = 256.
// LDS 14 KB. Pixels from global (L3-resident) both phases.  (R13 form)
// ---------------------------------------------------------------------------
__global__ __launch_bounds__(256, 4) void aff_agg_kernel(
    const float* __restrict__ x, const float* __restrict__ stok_pad,
    float* __restrict__ aff_g, float* __restrict__ asum_g,
    float* __restrict__ agg)
{
    __shared__ __align__(16) float sfs[9 * 260];   // sf9 [k][c]
    __shared__ __align__(16) float part[576];      // logits [p][k]
    __shared__ __align__(16) float affs[576];      // aff [k][p]

    int bid  = blockIdx.x;
    int xcd  = bid & 7, slot_ = bid >> 3;
    int pair = xcd * 128 + (slot_ >> 1);
    int m = pair & 7, i = (pair >> 3) & 15, b = pair >> 7;
    int j = m * 2 + (slot_ & 1);
    int bn = b * 256 + i * 16 + j;
    int t = threadIdx.x;

    // stage sf9 (channel-last, border-predicated): sfs[k][c]
    {
        const float* spT = stok_pad + (size_t)b * 324 * 256;
#pragma unroll
        for (int dy = 0; dy < 3; ++dy)
#pragma unroll
            for (int dx = 0; dx < 3; ++dx) {
                int r = i + dy, cn = j + dx;
                float v = 0.f;
                if ((unsigned)(r - 1) < 16u && (unsigned)(cn - 1) < 16u)
                    v = spT[((size_t)r * 18 + cn) * 256 + t];
                sfs[(dy * 3 + dx) * 260 + t] = v;
            }
    }
    part[t] = 0.f;
    part[t + 256] = 0.f;
    if (t < 64) part[t + 512] = 0.f;
    __syncthreads();

    int w = t >> 6, l = t & 63;

    // ---- phase 1: lane = (p-quad pq, c-16th cgl); acc[4p][9k] ----
    {
        int pq = l >> 2, cgl = l & 3;
        int cbase = w * 64 + cgl * 16;
        int pi = pq >> 1, pj4 = (pq & 1) * 4;
        const float* xb = x + (size_t)(b * 256) * 16384
                            + (size_t)(i * 8 + pi) * 128 + j * 8 + pj4;
        float acc[4][9];
#pragma unroll
        for (int ii = 0; ii < 4; ++ii)
#pragma unroll
            for (int k = 0; k < 9; ++k) acc[ii][k] = 0.f;

#pragma unroll
        for (int c4i = 0; c4i < 4; ++c4i) {
            int c = cbase + c4i * 4;
            const float4 p0 = *(const float4*)&xb[(size_t)(c + 0) * 16384];
            const float4 p1 = *(const float4*)&xb[(size_t)(c + 1) * 16384];
            const float4 p2 = *(const float4*)&xb[(size_t)(c + 2) * 16384];
            const float4 p3 = *(const float4*)&xb[(size_t)(c + 3) * 16384];
#pragma unroll
            for (int k = 0; k < 9; ++k) {
                const float4 sv = *(const float4*)&sfs[k * 260 + c];
                acc[0][k] += p0.x * sv.x + p1.x * sv.y + p2.x * sv.z + p3.x * sv.w;
                acc[1][k] += p0.y * sv.x + p1.y * sv.y + p2.y * sv.z + p3.y * sv.w;
                acc[2][k] += p0.z * sv.x + p1.z * sv.y + p2.z * sv.z + p3.z * sv.w;
                acc[3][k] += p0.w * sv.x + p1.w * sv.y + p2.w * sv.z + p3.w * sv.w;
            }
        }
#pragma unroll
        for (int ii = 0; ii < 4; ++ii)
#pragma unroll
            for (int k = 0; k < 9; ++k) {
                acc[ii][k] = dpp_add_xor1(acc[ii][k]);
                acc[ii][k] = dpp_add_xor2(acc[ii][k]);
            }
#pragma unroll
        for (int k = 0; k < 9; ++k) {
            float v01 = (cgl & 1) ? acc[1][k] : acc[0][k];
            float v23 = (cgl & 1) ? acc[3][k] : acc[2][k];
            float vk  = (cgl & 2) ? v23 : v01;
            atomicAdd(&part[l * 9 + k], vk);
        }
    }
    __syncthreads();

    // ---- phase 1.5: softmax over 9 (wave 0) ----
    if (t < 64) {
        float a[9];
        float mx = -1e30f;
#pragma unroll
        for (int k = 0; k < 9; ++k) {
            float v = part[t * 9 + k] * AFF_SCALE;
            a[k] = v;
            mx = fmaxf(mx, v);
        }
        float ssum = 0.f;
#pragma unroll
        for (int k = 0; k < 9; ++k) { a[k] = __expf(a[k] - mx); ssum += a[k]; }
        float inv = 1.f / ssum;
#pragma unroll
        for (int k = 0; k < 9; ++k) {
            a[k] *= inv;
            affs[k * 64 + t] = a[k];
            aff_g[(size_t)bn * 576 + k * 64 + t] = a[k];
        }
#pragma unroll
        for (int k = 0; k < 9; ++k) {
            float r = a[k];
            r += __shfl_down(r, 32, 64); r += __shfl_down(r, 16, 64);
            r += __shfl_down(r, 8, 64);  r += __shfl_down(r, 4, 64);
            r += __shfl_down(r, 2, 64);  r += __shfl_down(r, 1, 64);
            if (t == 0) asum_g[(size_t)bn * 9 + k] = r;
        }
    }
    __syncthreads();

    // ---- phase 2: lane = (c-quad cql, p-16th pq2); acc2[4c][9k] ----
    {
        int cql = l >> 2, pq2 = l & 3;
        int cb2 = w * 64 + cql * 4;
        const float* xb = x + (size_t)(b * 256) * 16384 + (size_t)(i * 8) * 128 + j * 8;
        float acc2[4][9];
#pragma unroll
        for (int ii = 0; ii < 4; ++ii)
#pragma unroll
            for (int k = 0; k < 9; ++k) acc2[ii][k] = 0.f;

#pragma unroll
        for (int pp = 0; pp < 4; ++pp) {
            int p4 = pq2 * 4 + pp;
            int pi = p4 >> 1, pj4 = (p4 & 1) * 4;
            const float* xr = xb + (size_t)pi * 128 + pj4;
            const float4 q0 = *(const float4*)&xr[(size_t)(cb2 + 0) * 16384];
            const float4 q1 = *(const float4*)&xr[(size_t)(cb2 + 1) * 16384];
            const float4 q2 = *(const float4*)&xr[(size_t)(cb2 + 2) * 16384];
            const float4 q3 = *(const float4*)&xr[(size_t)(cb2 + 3) * 16384];
#pragma unroll
            for (int k = 0; k < 9; ++k) {
                const float4 av = *(const float4*)&affs[k * 64 + p4 * 4];
                acc2[0][k] += q0.x * av.x + q0.y * av.y + q0.z * av.z + q0.w * av.w;
                acc2[1][k] += q1.x * av.x + q1.y * av.y + q1.z * av.z + q1.w * av.w;
                acc2[2][k] += q2.x * av.x + q2.y * av.y + q2.z * av.z + q2.w * av.w;
                acc2[3][k] += q3.x * av.x + q3.y * av.y + q3.z * av.z + q3.w * av.w;
            }
        }
#pragma unroll
        for (int ii = 0; ii < 4; ++ii)
#pragma unroll
            for (int k = 0; k < 9; ++k) {
                acc2[ii][k] = dpp_add_xor1(acc2[ii][k]);
                acc2[ii][k] = dpp_add_xor2(acc2[ii][k]);
            }
        int cout = w * 64 + l;
#pragma unroll
        for (int k = 0; k < 9; ++k) {
            float v01 = (pq2 & 1) ? acc2[1][k] : acc2[0][k];
            float v23 = (pq2 & 1) ? acc2[3][k] : acc2[2][k];
            float vk  = (pq2 & 2) ? v23 : v01;
            agg[((size_t)bn * 9 + k) * 256 + cout] = vk;
        }
    }
}

// ---------------------------------------------------------------------------
// K3: fold(agg)/(fold(asum)+1e-12) -> sf[b][c][n]. grid = B*16*2 (b,y,chalf),
// block 256.
// ---------------------------------------------------------------------------
__global__ __launch_bounds__(256) void fold_div_kernel(
    const float* __restrict__ agg, const float* __restrict__ asum_g,
    float* __restrict__ sf)
{
    __shared__ float v[128 * 17];
    int bid = blockIdx.x;
    int b = bid >> 5, y = (bid >> 1) & 15, ch = bid & 1;
    int t = threadIdx.x;
    int cl = t & 127, xp = t >> 7;     // c-local, x-parity
    for (int it = 0; it < 8; ++it) {
        int x = it * 2 + xp;
        float af = 0.f, val = 0.f;
#pragma unroll
        for (int dy = 0; dy < 3; ++dy)
#pragma unroll
            for (int dx = 0; dx < 3; ++dx) {
                int ii = y + 1 - dy, jj = x + 1 - dx;
                if ((unsigned)ii < 16u && (unsigned)jj < 16u) {
                    int idx = (b * 256 + ii * 16 + jj) * 9 + dy * 3 + dx;
                    af  += asum_g[idx];                              // uniform
                    val += agg[(size_t)idx * 256 + ch * 128 + cl];   // coalesced
                }
            }
        v[cl * 17 + x] = val / (af + 1e-12f);
    }
    __syncthreads();
    int xw = t & 15, cw = t >> 4;      // 16 c-groups
#pragma unroll
    for (int itc = 0; itc < 8; ++itc) {
        int c_local = cw + itc * 16;
        sf[((size_t)b * 256 + ch * 128 + c_local) * 256 + y * 16 + xw] =
            v[c_local * 17 + xw];
    }
}

// ---------------------------------------------------------------------------
// K4/K7: GEMM 32o x 64n tiles. mode 0: out[b][o][n] -> [b][M][256].
// mode 1: write padded [b][18][18][256] at +1 spatial offset.
// ---------------------------------------------------------------------------
__global__ __launch_bounds__(256) void gemm32(
    const float* __restrict__ A, const float* __restrict__ Bm,
    float* __restrict__ Cout, int M, int mode)
{
    __shared__ float As[32 * 36];   // [k][o], 32x32 tile, +4 pad
    __shared__ float Bs[32 * 64];
    int b = blockIdx.x, o0 = blockIdx.y * 32, n0 = blockIdx.z * 64;
    int t = threadIdx.x;
    int tr = t >> 4, tc = t & 15;      // tr: 16 o-pairs, tc: 16 n-quads
    const float* Bb = Bm + (size_t)b * 256 * 256;
    float acc[2][4];
#pragma unroll
    for (int ii = 0; ii < 2; ++ii)
#pragma unroll
        for (int jj = 0; jj < 4; ++jj) acc[ii][jj] = 0.f;

    for (int k0 = 0; k0 < 256; k0 += 32) {
        {
            int ol = t & 31, kq = (t >> 5) * 4;
            const float* Ap = A + (size_t)(o0 + ol) * 256 + k0 + kq;
            const float4 f = *(const float4*)&Ap[0];
            As[(kq + 0) * 36 + ol] = f.x; As[(kq + 1) * 36 + ol] = f.y;
            As[(kq + 2) * 36 + ol] = f.z; As[(kq + 3) * 36 + ol] = f.w;
        }
#pragma unroll
        for (int i2 = 0; i2 < 8; ++i2) {
            int e = t + i2 * 256;
            int kl = e >> 6, nl = e & 63;
            Bs[kl * 64 + nl] = Bb[(size_t)(k0 + kl) * 256 + n0 + nl];
        }
        __syncthreads();
#pragma unroll
        for (int kk = 0; kk < 32; ++kk) {
            const float2 av = *(const float2*)&As[kk * 36 + tr * 2];
            const float4 bv = *(const float4*)&Bs[kk * 64 + tc * 4];
            acc[0][0] += av.x * bv.x; acc[0][1] += av.x * bv.y;
            acc[0][2] += av.x * bv.z; acc[0][3] += av.x * bv.w;
            acc[1][0] += av.y * bv.x; acc[1][1] += av.y * bv.y;
            acc[1][2] += av.y * bv.z; acc[1][3] += av.y * bv.w;
        }
        __syncthreads();
    }

    if (mode == 0) {
#pragma unroll
        for (int ii = 0; ii < 2; ++ii) {
            int o = o0 + tr * 2 + ii;
            float4 st = make_float4(acc[ii][0], acc[ii][1], acc[ii][2], acc[ii][3]);
            *(float4*)&Cout[((size_t)b * M + o) * 256 + n0 + tc * 4] = st;
        }
    } else {
#pragma unroll
        for (int jj = 0; jj < 4; ++jj) {
            int n = n0 + tc * 4 + jj;
            int y = n >> 4, x = n & 15;
            float2 st = make_float2(acc[0][jj], acc[1][jj]);
            *(float2*)&Cout[(((size_t)b * 18 + 1 + y) * 18 + 1 + x) * 256 + o0 + tr * 2] = st;
        }
    }
}

// ---------------------------------------------------------------------------
// K5: attention + fused PE. grid = (8 b, 8 h, 8 n-tiles of 32), block = 256.
// R13 structure exactly; kv stride 32 -> 36 (PE reads 32-way -> 2-way).
// LDS 73.9 KB -> 2 blocks/CU.
// ---------------------------------------------------------------------------
__global__ __launch_bounds__(256) void attn_kernel(
    const float* __restrict__ qkv, const float* __restrict__ w_pe,
    float* __restrict__ o_attn)
{
    __shared__ __align__(16) float kv[256 * 36];  // K then V, [m][36]
    __shared__ float op[256 * 33];                // per-(mq,n) partial O
    __shared__ float mxsm[512];                   // per-(mq,n) {max, sum}
    __shared__ float wpe_s[288];                  // w_pe[h][d][9]
    int b = blockIdx.x, h = blockIdx.y, nt = blockIdx.z;
    int t = threadIdx.x, nl = t & 31, mq = t >> 5;   // 8 m-groups of 32 keys
    int n = nt * 32 + nl;

    {
        int dd = t >> 3, mb = (t & 7) * 32;
        const float* krow = qkv + ((size_t)b * 768 + h * 96 + 32 + dd) * 256;
#pragma unroll
        for (int e4 = 0; e4 < 8; ++e4) {
            int m = mb + e4 * 4;
            const float4 kw = *(const float4*)&krow[m];
            kv[(m + 0) * 36 + dd] = kw.x; kv[(m + 1) * 36 + dd] = kw.y;
            kv[(m + 2) * 36 + dd] = kw.z; kv[(m + 3) * 36 + dd] = kw.w;
        }
    }
    for (int e = t; e < 288; e += 256) wpe_s[e] = w_pe[h * 288 + e];

    float q[32];
    {
        const float* qbase = qkv + ((size_t)b * 768 + h * 96) * 256 + n;
#pragma unroll
        for (int d = 0; d < 32; ++d) q[d] = qbase[(size_t)d * 256];
    }
    __syncthreads();

    float l[32];
#pragma unroll
    for (int e = 0; e < 32; ++e) {
        const float* kp = &kv[(mq * 32 + e) * 36];
        float s = 0.f;
#pragma unroll
        for (int d4 = 0; d4 < 8; ++d4) {
            const float4 kv4 = *(const float4*)&kp[d4 * 4];
            s += q[d4 * 4 + 0] * kv4.x + q[d4 * 4 + 1] * kv4.y +
                 q[d4 * 4 + 2] * kv4.z + q[d4 * 4 + 3] * kv4.w;
        }
        l[e] = s * ATTN_SCALE;
    }
    float mx = -1e30f;
#pragma unroll
    for (int e = 0; e < 32; ++e) mx = fmaxf(mx, l[e]);
    float sm = 0.f;
#pragma unroll
    for (int e = 0; e < 32; ++e) { l[e] = __expf(l[e] - mx); sm += l[e]; }
    __syncthreads();

    {
        int dd = t >> 3, mb = (t & 7) * 32;
        const float* vrow = qkv + ((size_t)b * 768 + h * 96 + 64 + dd) * 256;
#pragma unroll
        for (int e4 = 0; e4 < 8; ++e4) {
            int m = mb + e4 * 4;
            const float4 vw = *(const float4*)&vrow[m];
            kv[(m + 0) * 36 + dd] = vw.x; kv[(m + 1) * 36 + dd] = vw.y;
            kv[(m + 2) * 36 + dd] = vw.z; kv[(m + 3) * 36 + dd] = vw.w;
        }
    }
    __syncthreads();

    float oa[32];
#pragma unroll
    for (int d = 0; d < 32; ++d) oa[d] = 0.f;
#pragma unroll
    for (int e = 0; e < 32; ++e) {
        float pm = l[e];
        const float* vp = &kv[(mq * 32 + e) * 36];
#pragma unroll
        for (int d4 = 0; d4 < 8; ++d4) {
            const float4 vv = *(const float4*)&vp[d4 * 4];
            oa[d4 * 4 + 0] += pm * vv.x; oa[d4 * 4 + 1] += pm * vv.y;
            oa[d4 * 4 + 2] += pm * vv.z; oa[d4 * 4 + 3] += pm * vv.w;
        }
    }

    {
        int idx = mq * 32 + nl;
#pragma unroll
        for (int d = 0; d < 32; ++d) op[idx * 33 + d] = oa[d];
        mxsm[idx * 2 + 0] = mx;
        mxsm[idx * 2 + 1] = sm;
    }
    __syncthreads();

    if (t < 32) {
        float M2 = -1e30f;
#pragma unroll
        for (int q8 = 0; q8 < 8; ++q8) M2 = fmaxf(M2, mxsm[(q8 * 32 + t) * 2]);
        float w[8], S = 0.f;
#pragma unroll
        for (int q8 = 0; q8 < 8; ++q8) {
            w[q8] = __expf(mxsm[(q8 * 32 + t) * 2] - M2);
            S += mxsm[(q8 * 32 + t) * 2 + 1] * w[q8];
        }
        float inv = 1.f / S;
        int n2 = nt * 32 + t;
        int y0 = n2 >> 4, x0 = n2 & 15;
#pragma unroll
        for (int d = 0; d < 32; ++d) {
            float o = 0.f;
#pragma unroll
            for (int q8 = 0; q8 < 8; ++q8) o += op[(q8 * 32 + t) * 33 + d] * w[q8];
            float pe = 0.f;
#pragma unroll
            for (int ky = 0; ky < 3; ++ky)
#pragma unroll
                for (int kx = 0; kx < 3; ++kx) {
                    int yv = y0 + ky - 1, xv = x0 + kx - 1;
                    if ((unsigned)yv < 16u && (unsigned)xv < 16u)
                        pe += wpe_s[d * 9 + ky * 3 + kx] * kv[(yv * 16 + xv) * 36 + d];
                }
            o_attn[((size_t)b * 256 + h * 32 + d) * 256 + n2] = o * inv + pe;
        }
    }
}

// ---------------------------------------------------------------------------
// K8: scatter v3. grid = (b,i,pi) = 1024 blocks, block = 256.
// sfa staging border-predicated (pad ring never written -> select 0).
// ---------------------------------------------------------------------------
__global__ __launch_bounds__(256) void scatter_kernel(
    const float* __restrict__ sfa_pad, const float* __restrict__ aff_g,
    float* __restrict__ out)
{
    __shared__ float ss[3 * 18 * 40];   // [dy][col][idx=q*8+d], stride 40
    __shared__ float aff_s[16 * 577];   // [j][p*9+k], stride 577 (>=576)

    int blk = blockIdx.x;
    int pi = blk & 7, i = (blk >> 3) & 15, b = blk >> 7;
    int t = threadIdx.x;

    for (int e = t; e < 1728; e += 256) {
        int dy = e / 576, rem = e % 576;
        int col = rem >> 5, idx = rem & 31;
        int q = idx >> 3, d = idx & 7;
        int row = i + dy;
        float v = 0.f;
        if ((unsigned)(row - 1) < 16u && (unsigned)(col - 1) < 16u)
            v = sfa_pad[(((size_t)b * 18 + row) * 18 + col) * 256 + q * 64 + pi * 8 + d];
        ss[(dy * 18 + col) * 40 + idx] = v;
    }
    {
        const float* ag = aff_g + ((size_t)b * 256 + i * 16) * 576;
        for (int e = t; e < 9216; e += 256) {
            int j = e / 576, rem = e % 576;
            int k = rem >> 6, p = rem & 63;
            aff_s[j * 577 + p * 9 + k] = ag[j * 576 + rem];
        }
    }
    __syncthreads();

    int lane = t & 63, w = t >> 6;
    int j0 = lane >> 3, pj = lane & 7;
    int j1 = j0 + 8;

    float S0[4][9], S1[4][9];
#pragma unroll
    for (int q = 0; q < 4; ++q)
#pragma unroll
        for (int k = 0; k < 9; ++k) {
            int dy = k / 3, dx = k % 3;
            S0[q][k] = ss[(dy * 18 + j0 + dx) * 40 + q * 8 + pj];
            S1[q][k] = ss[(dy * 18 + j1 + dx) * 40 + q * 8 + pj];
        }

    int y = i * 8 + pi;
    size_t ob = (size_t)b * 256 * 16384 + (size_t)y * 128;
    const float* A0 = &aff_s[j0 * 577];
    const float* A1 = &aff_s[j1 * 577];
    for (int p = w * 16; p < w * 16 + 16; ++p) {
        float a0[9], a1[9];
#pragma unroll
        for (int k = 0; k < 9; ++k) { a0[k] = A0[p * 9 + k]; a1[k] = A1[p * 9 + k]; }
#pragma unroll
        for (int q = 0; q < 4; ++q) {
            int c2 = p * 4 + q;
            float v0 = 0.f, v1 = 0.f;
#pragma unroll
            for (int k = 0; k < 9; ++k) {
                v0 += S0[q][k] * a0[k];
                v1 += S1[q][k] * a1[k];
            }
            out[ob + (size_t)c2 * 16384 + lane] = v0;
            out[ob + (size_t)c2 * 16384 + 64 + lane] = v1;
        }
    }
}

// ---------------------------------------------------------------------------
// launch. Workspace (floats), 15.8 MB; agg (18.9 MB) lives in d_out scratch
// (dead before scatter writes out). No memsets (predicated pad rings).
// ---------------------------------------------------------------------------
extern "C" void kernel_launch(void* const* d_in, const int* in_sizes, int n_in,
                              void* d_out, int out_size, void* d_ws, size_t ws_size,
                              hipStream_t stream) {
    const float* x      = (const float*)d_in[0];
    const float* w_qkv  = (const float*)d_in[1];
    const float* w_pe   = (const float*)d_in[2];
    const float* w_proj = (const float*)d_in[3];
    float* out = (float*)d_out;
    float* agg = (float*)d_out;  // scratch: 18.9 MB << 134 MB, dead before scatter

    float* ws = (float*)d_ws;
    const size_t o_aff  = 0;
    const size_t o_asum = 1179648;
    const size_t o_pad  = 1198080;
    const size_t o_sf   = 1861632;
    const size_t o_qkv  = 2385920;

    stoken_kernel<<<8 * 256 * 16, 128, 0, stream>>>(x, ws + o_pad);
    aff_agg_kernel<<<8 * 256, 256, 0, stream>>>(x, ws + o_pad, ws + o_aff,
                                                ws + o_asum, agg);
    fold_div_kernel<<<8 * 32, 256, 0, stream>>>(agg, ws + o_asum, ws + o_sf);
    gemm32<<<dim3(8, 24, 4), 256, 0, stream>>>(w_qkv, ws + o_sf, ws + o_qkv, 768, 0);
    attn_kernel<<<dim3(8, 8, 8), 256, 0, stream>>>(ws + o_qkv, w_pe, ws + o_sf);
    gemm32<<<dim3(8, 8, 4), 256, 0, stream>>>(w_proj, ws + o_sf, ws + o_pad, 256, 1);
    scatter_kernel<<<8 * 16 * 8, 256, 0, stream>>>(ws + o_pad, ws + o_aff, out);
}

// Round 11
// 416.718 us; speedup vs baseline: 1.1248x; 1.0112x over previous
//
#include <hip/hip_runtime.h>
#include <cstdint>
#include <cstddef>

// ---------------------------------------------------------------------------
// StokenAttention forward, MI355X. B=8, C=256, H=W=128, stoken 8x8 -> 16x16
// grid, n=256 stokens/batch, 64 px/stoken, NH=8 heads, HD=KD=32.
// R17: R16 (421.4 us, passed) with EXACTLY ONE change:
//  - aff_agg: 16 global float4 loads per phase hoisted into register arrays
//    (P[4][4]/Q[4][4], compile-time indexed) issued before the FMA chains,
//    KEEPING launch_bounds(256,4) (cap 128 VGPR; ~120 needed, fits).
//    Isolates R14's MLP hypothesis from its (256,3) confounder: at VGPR=60
//    only ~4 loads stay in flight -> ~4 serialized HBM exposures/phase,
//    matching the ~86 us plateau across four structural variants.
//  Watch: VGPR 60 -> ~100-126 (hoist took); attn ~109 recurrence would
//  confirm R14's co-compilation gremlin -> revert.
// ---------------------------------------------------------------------------

#define AFF_SCALE 0.0625f               // 256^-0.5
#define ATTN_SCALE 0.17677669529663687f // 32^-0.5

// DPP quad-perm add: v += lane(v ^ 1) / lane(v ^ 2) (VALU pipe).
__device__ __forceinline__ float dpp_add_xor1(float v) {
    int p = __builtin_amdgcn_update_dpp(0, __float_as_int(v), 0xB1, 0xF, 0xF, true);
    return v + __int_as_float(p);
}
__device__ __forceinline__ float dpp_add_xor2(float v) {
    int p = __builtin_amdgcn_update_dpp(0, __float_as_int(v), 0x4E, 0xF, 0xF, true);
    return v + __int_as_float(p);
}

// ---------------------------------------------------------------------------
// K1: stoken avg-pool. grid = B*C*16, block = 128. Channel-last
// [b][18][18][256]; interior (1..16)^2 only; ring handled by predication.
// ---------------------------------------------------------------------------
__global__ __launch_bounds__(128) void stoken_kernel(
    const float* __restrict__ x, float* __restrict__ stok_pad)
{
    int blk = blockIdx.x;
    int i  = blk & 15;
    int bc = blk >> 4;                 // b*256 + c
    int t  = threadIdx.x;              // col 0..127
    const float* xr = x + ((size_t)bc * 128 + i * 8) * 128 + t;
    float s = 0.f;
#pragma unroll
    for (int r = 0; r < 8; ++r) s += xr[r * 128];
    s += __shfl_down(s, 4, 64);
    s += __shfl_down(s, 2, 64);
    s += __shfl_down(s, 1, 64);
    if ((t & 7) == 0) {
        int j = t >> 3;  // 0..15
        int b = bc >> 8, c = bc & 255;
        stok_pad[(((size_t)b * 18 + (i + 1)) * 18 + (j + 1)) * 256 + c] =
            s * (1.f / 64.f);
    }
}

// ---------------------------------------------------------------------------
// K2: fused affinity + softmax + aggregation. grid = B*256, block = 256.
// LDS 14 KB. Pixels from global; 16 loads/phase hoisted (MLP).
// ---------------------------------------------------------------------------
__global__ __launch_bounds__(256, 4) void aff_agg_kernel(
    const float* __restrict__ x, const float* __restrict__ stok_pad,
    float* __restrict__ aff_g, float* __restrict__ asum_g,
    float* __restrict__ agg)
{
    __shared__ __align__(16) float sfs[9 * 260];   // sf9 [k][c]
    __shared__ __align__(16) float part[576];      // logits [p][k]
    __shared__ __align__(16) float affs[576];      // aff [k][p]

    int bid  = blockIdx.x;
    int xcd  = bid & 7, slot_ = bid >> 3;
    int pair = xcd * 128 + (slot_ >> 1);
    int m = pair & 7, i = (pair >> 3) & 15, b = pair >> 7;
    int j = m * 2 + (slot_ & 1);
    int bn = b * 256 + i * 16 + j;
    int t = threadIdx.x;

    // stage sf9 (channel-last, border-predicated): sfs[k][c]
    {
        const float* spT = stok_pad + (size_t)b * 324 * 256;
#pragma unroll
        for (int dy = 0; dy < 3; ++dy)
#pragma unroll
            for (int dx = 0; dx < 3; ++dx) {
                int r = i + dy, cn = j + dx;
                float v = 0.f;
                if ((unsigned)(r - 1) < 16u && (unsigned)(cn - 1) < 16u)
                    v = spT[((size_t)r * 18 + cn) * 256 + t];
                sfs[(dy * 3 + dx) * 260 + t] = v;
            }
    }
    part[t] = 0.f;
    part[t + 256] = 0.f;
    if (t < 64) part[t + 512] = 0.f;
    __syncthreads();

    int w = t >> 6, l = t & 63;

    // ---- phase 1: lane = (p-quad pq, c-16th cgl); acc[4p][9k].
    //      All 16 loads hoisted -> in flight together. ----
    {
        int pq = l >> 2, cgl = l & 3;
        int cbase = w * 64 + cgl * 16;
        int pi = pq >> 1, pj4 = (pq & 1) * 4;
        const float* xb = x + (size_t)(b * 256) * 16384
                            + (size_t)(i * 8 + pi) * 128 + j * 8 + pj4;

        float4 P[4][4];                // [c4i][c-sub], compile-time indexed
#pragma unroll
        for (int c4i = 0; c4i < 4; ++c4i) {
            int c = cbase + c4i * 4;
#pragma unroll
            for (int cs = 0; cs < 4; ++cs)
                P[c4i][cs] = *(const float4*)&xb[(size_t)(c + cs) * 16384];
        }

        float acc[4][9];
#pragma unroll
        for (int ii = 0; ii < 4; ++ii)
#pragma unroll
            for (int k = 0; k < 9; ++k) acc[ii][k] = 0.f;

#pragma unroll
        for (int c4i = 0; c4i < 4; ++c4i) {
            int c = cbase + c4i * 4;
            const float4 p0 = P[c4i][0], p1 = P[c4i][1];
            const float4 p2 = P[c4i][2], p3 = P[c4i][3];
#pragma unroll
            for (int k = 0; k < 9; ++k) {
                const float4 sv = *(const float4*)&sfs[k * 260 + c];
                acc[0][k] += p0.x * sv.x + p1.x * sv.y + p2.x * sv.z + p3.x * sv.w;
                acc[1][k] += p0.y * sv.x + p1.y * sv.y + p2.y * sv.z + p3.y * sv.w;
                acc[2][k] += p0.z * sv.x + p1.z * sv.y + p2.z * sv.z + p3.z * sv.w;
                acc[3][k] += p0.w * sv.x + p1.w * sv.y + p2.w * sv.z + p3.w * sv.w;
            }
        }
#pragma unroll
        for (int ii = 0; ii < 4; ++ii)
#pragma unroll
            for (int k = 0; k < 9; ++k) {
                acc[ii][k] = dpp_add_xor1(acc[ii][k]);
                acc[ii][k] = dpp_add_xor2(acc[ii][k]);
            }
#pragma unroll
        for (int k = 0; k < 9; ++k) {
            float v01 = (cgl & 1) ? acc[1][k] : acc[0][k];
            float v23 = (cgl & 1) ? acc[3][k] : acc[2][k];
            float vk  = (cgl & 2) ? v23 : v01;
            atomicAdd(&part[l * 9 + k], vk);
        }
    }
    __syncthreads();

    // ---- phase 1.5: softmax over 9 (wave 0) ----
    if (t < 64) {
        float a[9];
        float mx = -1e30f;
#pragma unroll
        for (int k = 0; k < 9; ++k) {
            float v = part[t * 9 + k] * AFF_SCALE;
            a[k] = v;
            mx = fmaxf(mx, v);
        }
        float ssum = 0.f;
#pragma unroll
        for (int k = 0; k < 9; ++k) { a[k] = __expf(a[k] - mx); ssum += a[k]; }
        float inv = 1.f / ssum;
#pragma unroll
        for (int k = 0; k < 9; ++k) {
            a[k] *= inv;
            affs[k * 64 + t] = a[k];
            aff_g[(size_t)bn * 576 + k * 64 + t] = a[k];
        }
#pragma unroll
        for (int k = 0; k < 9; ++k) {
            float r = a[k];
            r += __shfl_down(r, 32, 64); r += __shfl_down(r, 16, 64);
            r += __shfl_down(r, 8, 64);  r += __shfl_down(r, 4, 64);
            r += __shfl_down(r, 2, 64);  r += __shfl_down(r, 1, 64);
            if (t == 0) asum_g[(size_t)bn * 9 + k] = r;
        }
    }
    __syncthreads();

    // ---- phase 2: lane = (c-quad cql, p-16th pq2); acc2[4c][9k].
    //      All 16 loads hoisted -> in flight together. ----
    {
        int cql = l >> 2, pq2 = l & 3;
        int cb2 = w * 64 + cql * 4;
        const float* xb = x + (size_t)(b * 256) * 16384 + (size_t)(i * 8) * 128 + j * 8;

        float4 Q[4][4];                // [pp][c-sub]
#pragma unroll
        for (int pp = 0; pp < 4; ++pp) {
            int p4 = pq2 * 4 + pp;
            int pi = p4 >> 1, pj4 = (p4 & 1) * 4;
            const float* xr = xb + (size_t)pi * 128 + pj4;
#pragma unroll
            for (int cs = 0; cs < 4; ++cs)
                Q[pp][cs] = *(const float4*)&xr[(size_t)(cb2 + cs) * 16384];
        }

        float acc2[4][9];
#pragma unroll
        for (int ii = 0; ii < 4; ++ii)
#pragma unroll
            for (int k = 0; k < 9; ++k) acc2[ii][k] = 0.f;

#pragma unroll
        for (int pp = 0; pp < 4; ++pp) {
            int p4 = pq2 * 4 + pp;
            const float4 q0 = Q[pp][0], q1 = Q[pp][1];
            const float4 q2 = Q[pp][2], q3 = Q[pp][3];
#pragma unroll
            for (int k = 0; k < 9; ++k) {
                const float4 av = *(const float4*)&affs[k * 64 + p4 * 4];
                acc2[0][k] += q0.x * av.x + q0.y * av.y + q0.z * av.z + q0.w * av.w;
                acc2[1][k] += q1.x * av.x + q1.y * av.y + q1.z * av.z + q1.w * av.w;
                acc2[2][k] += q2.x * av.x + q2.y * av.y + q2.z * av.z + q2.w * av.w;
                acc2[3][k] += q3.x * av.x + q3.y * av.y + q3.z * av.z + q3.w * av.w;
            }
        }
#pragma unroll
        for (int ii = 0; ii < 4; ++ii)
#pragma unroll
            for (int k = 0; k < 9; ++k) {
                acc2[ii][k] = dpp_add_xor1(acc2[ii][k]);
                acc2[ii][k] = dpp_add_xor2(acc2[ii][k]);
            }
        int cout = w * 64 + l;
#pragma unroll
        for (int k = 0; k < 9; ++k) {
            float v01 = (pq2 & 1) ? acc2[1][k] : acc2[0][k];
            float v23 = (pq2 & 1) ? acc2[3][k] : acc2[2][k];
            float vk  = (pq2 & 2) ? v23 : v01;
            agg[((size_t)bn * 9 + k) * 256 + cout] = vk;
        }
    }
}

// ---------------------------------------------------------------------------
// K3: fold(agg)/(fold(asum)+1e-12) -> sf[b][c][n]. grid = B*16*2 (b,y,chalf),
// block 256.
// ---------------------------------------------------------------------------
__global__ __launch_bounds__(256) void fold_div_kernel(
    const float* __restrict__ agg, const float* __restrict__ asum_g,
    float* __restrict__ sf)
{
    __shared__ float v[128 * 17];
    int bid = blockIdx.x;
    int b = bid >> 5, y = (bid >> 1) & 15, ch = bid & 1;
    int t = threadIdx.x;
    int cl = t & 127, xp = t >> 7;     // c-local, x-parity
    for (int it = 0; it < 8; ++it) {
        int x = it * 2 + xp;
        float af = 0.f, val = 0.f;
#pragma unroll
        for (int dy = 0; dy < 3; ++dy)
#pragma unroll
            for (int dx = 0; dx < 3; ++dx) {
                int ii = y + 1 - dy, jj = x + 1 - dx;
                if ((unsigned)ii < 16u && (unsigned)jj < 16u) {
                    int idx = (b * 256 + ii * 16 + jj) * 9 + dy * 3 + dx;
                    af  += asum_g[idx];                              // uniform
                    val += agg[(size_t)idx * 256 + ch * 128 + cl];   // coalesced
                }
            }
        v[cl * 17 + x] = val / (af + 1e-12f);
    }
    __syncthreads();
    int xw = t & 15, cw = t >> 4;      // 16 c-groups
#pragma unroll
    for (int itc = 0; itc < 8; ++itc) {
        int c_local = cw + itc * 16;
        sf[((size_t)b * 256 + ch * 128 + c_local) * 256 + y * 16 + xw] =
            v[c_local * 17 + xw];
    }
}

// ---------------------------------------------------------------------------
// K4/K7: GEMM 32o x 64n tiles. mode 0: out[b][o][n] -> [b][M][256].
// mode 1: write padded [b][18][18][256] at +1 spatial offset.
// ---------------------------------------------------------------------------
__global__ __launch_bounds__(256) void gemm32(
    const float* __restrict__ A, const float* __restrict__ Bm,
    float* __restrict__ Cout, int M, int mode)
{
    __shared__ float As[32 * 36];   // [k][o], 32x32 tile, +4 pad
    __shared__ float Bs[32 * 64];
    int b = blockIdx.x, o0 = blockIdx.y * 32, n0 = blockIdx.z * 64;
    int t = threadIdx.x;
    int tr = t >> 4, tc = t & 15;      // tr: 16 o-pairs, tc: 16 n-quads
    const float* Bb = Bm + (size_t)b * 256 * 256;
    float acc[2][4];
#pragma unroll
    for (int ii = 0; ii < 2; ++ii)
#pragma unroll
        for (int jj = 0; jj < 4; ++jj) acc[ii][jj] = 0.f;

    for (int k0 = 0; k0 < 256; k0 += 32) {
        {
            int ol = t & 31, kq = (t >> 5) * 4;
            const float* Ap = A + (size_t)(o0 + ol) * 256 + k0 + kq;
            const float4 f = *(const float4*)&Ap[0];
            As[(kq + 0) * 36 + ol] = f.x; As[(kq + 1) * 36 + ol] = f.y;
            As[(kq + 2) * 36 + ol] = f.z; As[(kq + 3) * 36 + ol] = f.w;
        }
#pragma unroll
        for (int i2 = 0; i2 < 8; ++i2) {
            int e = t + i2 * 256;
            int kl = e >> 6, nl = e & 63;
            Bs[kl * 64 + nl] = Bb[(size_t)(k0 + kl) * 256 + n0 + nl];
        }
        __syncthreads();
#pragma unroll
        for (int kk = 0; kk < 32; ++kk) {
            const float2 av = *(const float2*)&As[kk * 36 + tr * 2];
            const float4 bv = *(const float4*)&Bs[kk * 64 + tc * 4];
            acc[0][0] += av.x * bv.x; acc[0][1] += av.x * bv.y;
            acc[0][2] += av.x * bv.z; acc[0][3] += av.x * bv.w;
            acc[1][0] += av.y * bv.x; acc[1][1] += av.y * bv.y;
            acc[1][2] += av.y * bv.z; acc[1][3] += av.y * bv.w;
        }
        __syncthreads();
    }

    if (mode == 0) {
#pragma unroll
        for (int ii = 0; ii < 2; ++ii) {
            int o = o0 + tr * 2 + ii;
            float4 st = make_float4(acc[ii][0], acc[ii][1], acc[ii][2], acc[ii][3]);
            *(float4*)&Cout[((size_t)b * M + o) * 256 + n0 + tc * 4] = st;
        }
    } else {
#pragma unroll
        for (int jj = 0; jj < 4; ++jj) {
            int n = n0 + tc * 4 + jj;
            int y = n >> 4, x = n & 15;
            float2 st = make_float2(acc[0][jj], acc[1][jj]);
            *(float2*)&Cout[(((size_t)b * 18 + 1 + y) * 18 + 1 + x) * 256 + o0 + tr * 2] = st;
        }
    }
}

// ---------------------------------------------------------------------------
// K5: attention + fused PE. grid = (8 b, 8 h, 8 n-tiles of 32), block = 256.
// kv stride 36 (PE reads 2-way instead of 32-way conflicts). LDS 73.9 KB.
// ---------------------------------------------------------------------------
__global__ __launch_bounds__(256) void attn_kernel(
    const float* __restrict__ qkv, const float* __restrict__ w_pe,
    float* __restrict__ o_attn)
{
    __shared__ __align__(16) float kv[256 * 36];  // K then V, [m][36]
    __shared__ float op[256 * 33];                // per-(mq,n) partial O
    __shared__ float mxsm[512];                   // per-(mq,n) {max, sum}
    __shared__ float wpe_s[288];                  // w_pe[h][d][9]
    int b = blockIdx.x, h = blockIdx.y, nt = blockIdx.z;
    int t = threadIdx.x, nl = t & 31, mq = t >> 5;   // 8 m-groups of 32 keys
    int n = nt * 32 + nl;

    {
        int dd = t >> 3, mb = (t & 7) * 32;
        const float* krow = qkv + ((size_t)b * 768 + h * 96 + 32 + dd) * 256;
#pragma unroll
        for (int e4 = 0; e4 < 8; ++e4) {
            int m = mb + e4 * 4;
            const float4 kw = *(const float4*)&krow[m];
            kv[(m + 0) * 36 + dd] = kw.x; kv[(m + 1) * 36 + dd] = kw.y;
            kv[(m + 2) * 36 + dd] = kw.z; kv[(m + 3) * 36 + dd] = kw.w;
        }
    }
    for (int e = t; e < 288; e += 256) wpe_s[e] = w_pe[h * 288 + e];

    float q[32];
    {
        const float* qbase = qkv + ((size_t)b * 768 + h * 96) * 256 + n;
#pragma unroll
        for (int d = 0; d < 32; ++d) q[d] = qbase[(size_t)d * 256];
    }
    __syncthreads();

    float l[32];
#pragma unroll
    for (int e = 0; e < 32; ++e) {
        const float* kp = &kv[(mq * 32 + e) * 36];
        float s = 0.f;
#pragma unroll
        for (int d4 = 0; d4 < 8; ++d4) {
            const float4 kv4 = *(const float4*)&kp[d4 * 4];
            s += q[d4 * 4 + 0] * kv4.x + q[d4 * 4 + 1] * kv4.y +
                 q[d4 * 4 + 2] * kv4.z + q[d4 * 4 + 3] * kv4.w;
        }
        l[e] = s * ATTN_SCALE;
    }
    float mx = -1e30f;
#pragma unroll
    for (int e = 0; e < 32; ++e) mx = fmaxf(mx, l[e]);
    float sm = 0.f;
#pragma unroll
    for (int e = 0; e < 32; ++e) { l[e] = __expf(l[e] - mx); sm += l[e]; }
    __syncthreads();

    {
        int dd = t >> 3, mb = (t & 7) * 32;
        const float* vrow = qkv + ((size_t)b * 768 + h * 96 + 64 + dd) * 256;
#pragma unroll
        for (int e4 = 0; e4 < 8; ++e4) {
            int m = mb + e4 * 4;
            const float4 vw = *(const float4*)&vrow[m];
            kv[(m + 0) * 36 + dd] = vw.x; kv[(m + 1) * 36 + dd] = vw.y;
            kv[(m + 2) * 36 + dd] = vw.z; kv[(m + 3) * 36 + dd] = vw.w;
        }
    }
    __syncthreads();

    float oa[32];
#pragma unroll
    for (int d = 0; d < 32; ++d) oa[d] = 0.f;
#pragma unroll
    for (int e = 0; e < 32; ++e) {
        float pm = l[e];
        const float* vp = &kv[(mq * 32 + e) * 36];
#pragma unroll
        for (int d4 = 0; d4 < 8; ++d4) {
            const float4 vv = *(const float4*)&vp[d4 * 4];
            oa[d4 * 4 + 0] += pm * vv.x; oa[d4 * 4 + 1] += pm * vv.y;
            oa[d4 * 4 + 2] += pm * vv.z; oa[d4 * 4 + 3] += pm * vv.w;
        }
    }

    {
        int idx = mq * 32 + nl;
#pragma unroll
        for (int d = 0; d < 32; ++d) op[idx * 33 + d] = oa[d];
        mxsm[idx * 2 + 0] = mx;
        mxsm[idx * 2 + 1] = sm;
    }
    __syncthreads();

    if (t < 32) {
        float M2 = -1e30f;
#pragma unroll
        for (int q8 = 0; q8 < 8; ++q8) M2 = fmaxf(M2, mxsm[(q8 * 32 + t) * 2]);
        float w[8], S = 0.f;
#pragma unroll
        for (int q8 = 0; q8 < 8; ++q8) {
            w[q8] = __expf(mxsm[(q8 * 32 + t) * 2] - M2);
            S += mxsm[(q8 * 32 + t) * 2 + 1] * w[q8];
        }
        float inv = 1.f / S;
        int n2 = nt * 32 + t;
        int y0 = n2 >> 4, x0 = n2 & 15;
#pragma unroll
        for (int d = 0; d < 32; ++d) {
            float o = 0.f;
#pragma unroll
            for (int q8 = 0; q8 < 8; ++q8) o += op[(q8 * 32 + t) * 33 + d] * w[q8];
            float pe = 0.f;
#pragma unroll
            for (int ky = 0; ky < 3; ++ky)
#pragma unroll
                for (int kx = 0; kx < 3; ++kx) {
                    int yv = y0 + ky - 1, xv = x0 + kx - 1;
                    if ((unsigned)yv < 16u && (unsigned)xv < 16u)
                        pe += wpe_s[d * 9 + ky * 3 + kx] * kv[(yv * 16 + xv) * 36 + d];
                }
            o_attn[((size_t)b * 256 + h * 32 + d) * 256 + n2] = o * inv + pe;
        }
    }
}

// ---------------------------------------------------------------------------
// K8: scatter v3. grid = (b,i,pi) = 1024 blocks, block = 256.
// sfa staging border-predicated (pad ring never written -> select 0).
// ---------------------------------------------------------------------------
__global__ __launch_bounds__(256) void scatter_kernel(
    const float* __restrict__ sfa_pad, const float* __restrict__ aff_g,
    float* __restrict__ out)
{
    __shared__ float ss[3 * 18 * 40];   // [dy][col][idx=q*8+d], stride 40
    __shared__ float aff_s[16 * 577];   // [j][p*9+k], stride 577 (>=576)

    int blk = blockIdx.x;
    int pi = blk & 7, i = (blk >> 3) & 15, b = blk >> 7;
    int t = threadIdx.x;

    for (int e = t; e < 1728; e += 256) {
        int dy = e / 576, rem = e % 576;
        int col = rem >> 5, idx = rem & 31;
        int q = idx >> 3, d = idx & 7;
        int row = i + dy;
        float v = 0.f;
        if ((unsigned)(row - 1) < 16u && (unsigned)(col - 1) < 16u)
            v = sfa_pad[(((size_t)b * 18 + row) * 18 + col) * 256 + q * 64 + pi * 8 + d];
        ss[(dy * 18 + col) * 40 + idx] = v;
    }
    {
        const float* ag = aff_g + ((size_t)b * 256 + i * 16) * 576;
        for (int e = t; e < 9216; e += 256) {
            int j = e / 576, rem = e % 576;
            int k = rem >> 6, p = rem & 63;
            aff_s[j * 577 + p * 9 + k] = ag[j * 576 + rem];
        }
    }
    __syncthreads();

    int lane = t & 63, w = t >> 6;
    int j0 = lane >> 3, pj = lane & 7;
    int j1 = j0 + 8;

    float S0[4][9], S1[4][9];
#pragma unroll
    for (int q = 0; q < 4; ++q)
#pragma unroll
        for (int k = 0; k < 9; ++k) {
            int dy = k / 3, dx = k % 3;
            S0[q][k] = ss[(dy * 18 + j0 + dx) * 40 + q * 8 + pj];
            S1[q][k] = ss[(dy * 18 + j1 + dx) * 40 + q * 8 + pj];
        }

    int y = i * 8 + pi;
    size_t ob = (size_t)b * 256 * 16384 + (size_t)y * 128;
    const float* A0 = &aff_s[j0 * 577];
    const float* A1 = &aff_s[j1 * 577];
    for (int p = w * 16; p < w * 16 + 16; ++p) {
        float a0[9], a1[9];
#pragma unroll
        for (int k = 0; k < 9; ++k) { a0[k] = A0[p * 9 + k]; a1[k] = A1[p * 9 + k]; }
#pragma unroll
        for (int q = 0; q < 4; ++q) {
            int c2 = p * 4 + q;
            float v0 = 0.f, v1 = 0.f;
#pragma unroll
            for (int k = 0; k < 9; ++k) {
                v0 += S0[q][k] * a0[k];
                v1 += S1[q][k] * a1[k];
            }
            out[ob + (size_t)c2 * 16384 + lane] = v0;
            out[ob + (size_t)c2 * 16384 + 64 + lane] = v1;
        }
    }
}

// ---------------------------------------------------------------------------
// launch. Workspace (floats), 15.8 MB; agg (18.9 MB) lives in d_out scratch
// (dead before scatter writes out). No memsets (predicated pad rings).
// ---------------------------------------------------------------------------
extern "C" void kernel_launch(void* const* d_in, const int* in_sizes, int n_in,
                              void* d_out, int out_size, void* d_ws, size_t ws_size,
                              hipStream_t stream) {
    const float* x      = (const float*)d_in[0];
    const float* w_qkv  = (const float*)d_in[1];
    const float* w_pe   = (const float*)d_in[2];
    const float* w_proj = (const float*)d_in[3];
    float* out = (float*)d_out;
    float* agg = (float*)d_out;  // scratch: 18.9 MB << 134 MB, dead before scatter

    float* ws = (float*)d_ws;
    const size_t o_aff  = 0;
    const size_t o_asum = 1179648;
    const size_t o_pad  = 1198080;
    const size_t o_sf   = 1861632;
    const size_t o_qkv  = 2385920;

    stoken_kernel<<<8 * 256 * 16, 128, 0, stream>>>(x, ws + o_pad);
    aff_agg_kernel<<<8 * 256, 256, 0, stream>>>(x, ws + o_pad, ws + o_aff,
                                                ws + o_asum, agg);
    fold_div_kernel<<<8 * 32, 256, 0, stream>>>(agg, ws + o_asum, ws + o_sf);
    gemm32<<<dim3(8, 24, 4), 256, 0, stream>>>(w_qkv, ws + o_sf, ws + o_qkv, 768, 0);
    attn_kernel<<<dim3(8, 8, 8), 256, 0, stream>>>(ws + o_qkv, w_pe, ws + o_sf);
    gemm32<<<dim3(8, 8, 4), 256, 0, stream>>>(w_proj, ws + o_sf, ws + o_pad, 256, 1);
    scatter_kernel<<<8 * 16 * 8, 256, 0, stream>>>(ws + o_pad, ws + o_aff, out);
}